// Round 4
// baseline (405.084 us; speedup 1.0000x reference)
//
#include <hip/hip_runtime.h>
#include <hip/hip_bf16.h>

typedef __attribute__((ext_vector_type(8))) short bf16x8;
typedef __attribute__((ext_vector_type(4))) float f32x4;

#define K_DIM 64

// ---------------- prep: one wave per row ----------------
// Split f32 row into bf16 hi/lo planes, compute row norm (exact fp32),
// and (for centres) inv_sigma2 = exp(-2*log_sigmas).
__global__ __launch_bounds__(256) void rbf_prep(
    const float* __restrict__ src, int rows,
    __hip_bfloat16* __restrict__ hi, __hip_bfloat16* __restrict__ lo,
    float* __restrict__ norms,
    const float* __restrict__ log_sigmas, float* __restrict__ inv_sigma2)
{
    int row  = blockIdx.x * 4 + (threadIdx.x >> 6);
    int lane = threadIdx.x & 63;
    if (row >= rows) return;

    float v = src[(size_t)row * K_DIM + lane];
    __hip_bfloat16 h = __float2bfloat16(v);
    float hf = __bfloat162float(h);
    __hip_bfloat16 l = __float2bfloat16(v - hf);
    hi[(size_t)row * K_DIM + lane] = h;
    lo[(size_t)row * K_DIM + lane] = l;

    float s = v * v;
    #pragma unroll
    for (int off = 32; off > 0; off >>= 1) s += __shfl_down(s, off, 64);
    if (lane == 0) {
        norms[row] = s;
        if (inv_sigma2) inv_sigma2[row] = __expf(-2.0f * log_sigmas[row]);
    }
}

// ---------------- main ----------------
// Block 64(M) x 64(N), 4 waves; wave owns M-strip of 16 rows, all 64 N.
// OPERANDS SWAPPED vs R2/R3: A = centres, B = x. With measured layouts
//   A: i = lane&15 (centre row), k = quad*8+j
//   B: j = lane&15 (x row),      k = quad*8+j
//   D: col = lane&15 -> M index, row = quad*4+reg -> N index
// => each lane's 4 acc regs are 4 CONSECUTIVE N columns of one output row
// => epilogue stores are global_store_dwordx4 (16 B/lane, 1 KB/wave-instr),
//    4x fewer store instrs than the D-row-major orientation (R3 was store-
//    queue limited at 1.68 TB/s with 4 B/lane stores).
// Split-bf16: dot ~ chi*xhi + chi*xlo + clo*xhi (lo*lo dropped, err ~2e-3).
__global__ __launch_bounds__(256) void rbf_main(
    const __hip_bfloat16* __restrict__ xhi, const __hip_bfloat16* __restrict__ xlo,
    const __hip_bfloat16* __restrict__ chi, const __hip_bfloat16* __restrict__ clo,
    const float* __restrict__ nx, const float* __restrict__ nc,
    const float* __restrict__ inv_sigma2,
    float* __restrict__ out, int N)
{
    const int wave = threadIdx.x >> 6;
    const int lane = threadIdx.x & 63;
    const int quad = lane >> 4;
    const int l16  = lane & 15;

    const int m_base = (blockIdx.y << 6) + (wave << 4);
    const int n_base = blockIdx.x << 6;

    // B fragments: this wave's 16 x-rows, reused across all 4 N-tiles.
    const int bm = m_base + l16;
    const bf16x8 xh0 = *(const bf16x8*)(xhi + (size_t)bm * K_DIM +      quad * 8);
    const bf16x8 xh1 = *(const bf16x8*)(xhi + (size_t)bm * K_DIM + 32 + quad * 8);
    const bf16x8 xl0 = *(const bf16x8*)(xlo + (size_t)bm * K_DIM +      quad * 8);
    const bf16x8 xl1 = *(const bf16x8*)(xlo + (size_t)bm * K_DIM + 32 + quad * 8);
    const float  nxm = nx[bm];                    // ||x_m||^2, per-lane scalar

    #pragma unroll 1   // keep VGPR <= ~64 for 8 waves/SIMD
    for (int nt = 0; nt < 4; ++nt) {
        const int ntile = n_base + nt * 16;

        // A fragments: 16 centre rows of this N-tile.
        const int an = ntile + l16;
        const bf16x8 ch0 = *(const bf16x8*)(chi + (size_t)an * K_DIM +      quad * 8);
        const bf16x8 ch1 = *(const bf16x8*)(chi + (size_t)an * K_DIM + 32 + quad * 8);
        const bf16x8 cl0 = *(const bf16x8*)(clo + (size_t)an * K_DIM +      quad * 8);
        const bf16x8 cl1 = *(const bf16x8*)(clo + (size_t)an * K_DIM + 32 + quad * 8);

        f32x4 acc = {0.f, 0.f, 0.f, 0.f};
        acc = __builtin_amdgcn_mfma_f32_16x16x32_bf16(ch0, xh0, acc, 0, 0, 0);
        acc = __builtin_amdgcn_mfma_f32_16x16x32_bf16(ch1, xh1, acc, 0, 0, 0);
        acc = __builtin_amdgcn_mfma_f32_16x16x32_bf16(ch0, xl0, acc, 0, 0, 0);
        acc = __builtin_amdgcn_mfma_f32_16x16x32_bf16(ch1, xl1, acc, 0, 0, 0);
        acc = __builtin_amdgcn_mfma_f32_16x16x32_bf16(cl0, xh0, acc, 0, 0, 0);
        acc = __builtin_amdgcn_mfma_f32_16x16x32_bf16(cl1, xh1, acc, 0, 0, 0);

        // This lane's 4 output columns: ntile + quad*4 .. +3 (16B aligned).
        const int nw = ntile + quad * 4;
        const f32x4 nc4 = *(const f32x4*)(nc + nw);
        const f32x4 iv4 = *(const f32x4*)(inv_sigma2 + nw);
        f32x4 res;
        #pragma unroll
        for (int r = 0; r < 4; ++r) {
            float sq = fmaxf(nxm + nc4[r] - 2.0f * acc[r], 0.f);
            res[r] = __expf(-sq * iv4[r]);
        }
        *(f32x4*)(out + (size_t)bm * N + nw) = res;
    }
}

// ---------------- fallback: fully fused (R2's passing kernel) ----------------
__device__ __forceinline__ void split8(const float* __restrict__ p,
                                       bf16x8& hi, bf16x8& lo, float& ss) {
    #pragma unroll
    for (int j = 0; j < 8; ++j) {
        float v = p[j];
        ss = fmaf(v, v, ss);
        __hip_bfloat16 h = __float2bfloat16(v);
        float hf = __bfloat162float(h);
        __hip_bfloat16 l = __float2bfloat16(v - hf);
        hi[j] = *reinterpret_cast<const short*>(&h);
        lo[j] = *reinterpret_cast<const short*>(&l);
    }
}

__global__ __launch_bounds__(256) void rbf_fused(
    const float* __restrict__ x, const float* __restrict__ c,
    const float* __restrict__ ls, float* __restrict__ out, int N)
{
    const int wave = threadIdx.x >> 6;
    const int lane = threadIdx.x & 63;
    const int quad = lane >> 4;
    const int l16  = lane & 15;

    const int m_base = (blockIdx.y << 6) + (wave << 4);
    const int n_base = blockIdx.x << 6;

    const int am = m_base + l16;
    const float* xp = x + (size_t)am * K_DIM;
    bf16x8 ahi0, alo0, ahi1, alo1;
    float ssx = 0.f;
    split8(xp + quad * 8,      ahi0, alo0, ssx);
    split8(xp + 32 + quad * 8, ahi1, alo1, ssx);
    ssx += __shfl_xor(ssx, 16, 64);
    ssx += __shfl_xor(ssx, 32, 64);
    float nxr[4];
    #pragma unroll
    for (int r = 0; r < 4; ++r) nxr[r] = __shfl(ssx, quad * 4 + r, 64);

    #pragma unroll
    for (int nt = 0; nt < 4; ++nt) {
        const int n = n_base + nt * 16 + l16;
        const float* cp = c + (size_t)n * K_DIM;
        bf16x8 bhi0, blo0, bhi1, blo1;
        float ssc = 0.f;
        split8(cp + quad * 8,      bhi0, blo0, ssc);
        split8(cp + 32 + quad * 8, bhi1, blo1, ssc);
        ssc += __shfl_xor(ssc, 16, 64);
        ssc += __shfl_xor(ssc, 32, 64);

        f32x4 acc = {0.f, 0.f, 0.f, 0.f};
        acc = __builtin_amdgcn_mfma_f32_16x16x32_bf16(ahi0, bhi0, acc, 0, 0, 0);
        acc = __builtin_amdgcn_mfma_f32_16x16x32_bf16(ahi1, bhi1, acc, 0, 0, 0);
        acc = __builtin_amdgcn_mfma_f32_16x16x32_bf16(ahi0, blo0, acc, 0, 0, 0);
        acc = __builtin_amdgcn_mfma_f32_16x16x32_bf16(ahi1, blo1, acc, 0, 0, 0);
        acc = __builtin_amdgcn_mfma_f32_16x16x32_bf16(alo0, bhi0, acc, 0, 0, 0);
        acc = __builtin_amdgcn_mfma_f32_16x16x32_bf16(alo1, bhi1, acc, 0, 0, 0);

        const float invv = __expf(-2.0f * ls[n]);
        #pragma unroll
        for (int r = 0; r < 4; ++r) {
            const int row = m_base + quad * 4 + r;
            float sq = fmaxf(nxr[r] + ssc - 2.0f * acc[r], 0.f);
            out[(size_t)row * N + n] = __expf(-sq * invv);
        }
    }
}

extern "C" void kernel_launch(void* const* d_in, const int* in_sizes, int n_in,
                              void* d_out, int out_size, void* d_ws, size_t ws_size,
                              hipStream_t stream) {
    const float* x  = (const float*)d_in[0];   // [M,64]
    const float* c  = (const float*)d_in[1];   // [N,64]
    const float* ls = (const float*)d_in[2];   // [N]
    float* out = (float*)d_out;                // [M,N]

    const int M = in_sizes[0] / K_DIM;   // 16384
    const int N = in_sizes[2];           // 4096

    size_t off = 0;
    auto place = [&](size_t bytes) { size_t p = off; off += (bytes + 255) & ~(size_t)255; return p; };
    size_t o_xhi = place((size_t)M * K_DIM * 2);
    size_t o_xlo = place((size_t)M * K_DIM * 2);
    size_t o_chi = place((size_t)N * K_DIM * 2);
    size_t o_clo = place((size_t)N * K_DIM * 2);
    size_t o_nx  = place((size_t)M * 4);
    size_t o_nc  = place((size_t)N * 4);
    size_t o_inv = place((size_t)N * 4);

    if (ws_size >= off) {
        char* ws = (char*)d_ws;
        __hip_bfloat16* xhi = (__hip_bfloat16*)(ws + o_xhi);
        __hip_bfloat16* xlo = (__hip_bfloat16*)(ws + o_xlo);
        __hip_bfloat16* chi = (__hip_bfloat16*)(ws + o_chi);
        __hip_bfloat16* clo = (__hip_bfloat16*)(ws + o_clo);
        float* nx  = (float*)(ws + o_nx);
        float* nc  = (float*)(ws + o_nc);
        float* inv = (float*)(ws + o_inv);

        rbf_prep<<<dim3((M + 3) / 4), 256, 0, stream>>>(x, M, xhi, xlo, nx, nullptr, nullptr);
        rbf_prep<<<dim3((N + 3) / 4), 256, 0, stream>>>(c, N, chi, clo, nc, ls, inv);
        rbf_main<<<dim3(N / 64, M / 64), 256, 0, stream>>>(xhi, xlo, chi, clo, nx, nc, inv, out, N);
    } else {
        rbf_fused<<<dim3(N / 64, M / 64), 256, 0, stream>>>(x, c, ls, out, N);
    }
}

// Round 5
// 392.817 us; speedup vs baseline: 1.0312x; 1.0312x over previous
//
#include <hip/hip_runtime.h>
#include <hip/hip_bf16.h>

typedef __attribute__((ext_vector_type(8))) short bf16x8;
typedef __attribute__((ext_vector_type(4))) float f32x4;

#define K_DIM 64

// ---------------- prep: one wave per row ----------------
__global__ __launch_bounds__(256) void rbf_prep(
    const float* __restrict__ src, int rows,
    __hip_bfloat16* __restrict__ hi, __hip_bfloat16* __restrict__ lo,
    float* __restrict__ norms,
    const float* __restrict__ log_sigmas, float* __restrict__ inv_sigma2)
{
    int row  = blockIdx.x * 4 + (threadIdx.x >> 6);
    int lane = threadIdx.x & 63;
    if (row >= rows) return;

    float v = src[(size_t)row * K_DIM + lane];
    __hip_bfloat16 h = __float2bfloat16(v);
    float hf = __bfloat162float(h);
    __hip_bfloat16 l = __float2bfloat16(v - hf);
    hi[(size_t)row * K_DIM + lane] = h;
    lo[(size_t)row * K_DIM + lane] = l;

    float s = v * v;
    #pragma unroll
    for (int off = 32; off > 0; off >>= 1) s += __shfl_down(s, off, 64);
    if (lane == 0) {
        norms[row] = s;
        if (inv_sigma2) inv_sigma2[row] = __expf(-2.0f * log_sigmas[row]);
    }
}

// ---------------- main ----------------
// Block = 16 M-rows x 256 N-cols, 4 waves. All waves share the same 16 rows
// (x-frags identical -> L1 hits); wave w owns cols [w*64, w*64+64).
// Compute orientation = R4 (verified): A = centres, B = x;
//   D: col(lane&15) -> M row, row(quad*4+reg) -> 4 consecutive N cols.
// Results bounce through LDS [16][260] f32 so the global stores are
// 64-lane-contiguous 1 KB dwordx4 per instruction (fill-kernel geometry:
// that pattern measures 6.0 TB/s at 10% occupancy in this harness's own
// fillBufferAligned; our previous 64 B-segment stores capped at ~1.6 TB/s).
#define LDS_PITCH 260   // 256 + 4: bank-group rotation per row, native-rate b128
__global__ __launch_bounds__(256, 6) void rbf_main(
    const __hip_bfloat16* __restrict__ xhi, const __hip_bfloat16* __restrict__ xlo,
    const __hip_bfloat16* __restrict__ chi, const __hip_bfloat16* __restrict__ clo,
    const float* __restrict__ nx, const float* __restrict__ nc,
    const float* __restrict__ inv_sigma2,
    float* __restrict__ out, int N)
{
    __shared__ float buf[16][LDS_PITCH];

    const int wave = threadIdx.x >> 6;
    const int lane = threadIdx.x & 63;
    const int quad = lane >> 4;
    const int l16  = lane & 15;

    const int m_base = blockIdx.y << 4;            // 16 rows per block
    const int n_base = blockIdx.x << 8;            // 256 cols per block
    const int n_wave = n_base + (wave << 6);       // this wave's 64-col strip

    // B fragments: the block's 16 x-rows (same for all 4 waves -> L1).
    const int bm = m_base + l16;
    const bf16x8 xh0 = *(const bf16x8*)(xhi + (size_t)bm * K_DIM +      quad * 8);
    const bf16x8 xh1 = *(const bf16x8*)(xhi + (size_t)bm * K_DIM + 32 + quad * 8);
    const bf16x8 xl0 = *(const bf16x8*)(xlo + (size_t)bm * K_DIM +      quad * 8);
    const bf16x8 xl1 = *(const bf16x8*)(xlo + (size_t)bm * K_DIM + 32 + quad * 8);
    const float  nxm = nx[bm];

    #pragma unroll 2
    for (int nt = 0; nt < 4; ++nt) {
        const int ntile = n_wave + nt * 16;

        const int an = ntile + l16;
        const bf16x8 ch0 = *(const bf16x8*)(chi + (size_t)an * K_DIM +      quad * 8);
        const bf16x8 ch1 = *(const bf16x8*)(chi + (size_t)an * K_DIM + 32 + quad * 8);
        const bf16x8 cl0 = *(const bf16x8*)(clo + (size_t)an * K_DIM +      quad * 8);
        const bf16x8 cl1 = *(const bf16x8*)(clo + (size_t)an * K_DIM + 32 + quad * 8);

        f32x4 acc = {0.f, 0.f, 0.f, 0.f};
        acc = __builtin_amdgcn_mfma_f32_16x16x32_bf16(ch0, xh0, acc, 0, 0, 0);
        acc = __builtin_amdgcn_mfma_f32_16x16x32_bf16(ch1, xh1, acc, 0, 0, 0);
        acc = __builtin_amdgcn_mfma_f32_16x16x32_bf16(ch0, xl0, acc, 0, 0, 0);
        acc = __builtin_amdgcn_mfma_f32_16x16x32_bf16(ch1, xl1, acc, 0, 0, 0);
        acc = __builtin_amdgcn_mfma_f32_16x16x32_bf16(cl0, xh0, acc, 0, 0, 0);
        acc = __builtin_amdgcn_mfma_f32_16x16x32_bf16(cl1, xh1, acc, 0, 0, 0);

        // Epilogue into LDS: lane's 4 consecutive cols of row l16.
        const int nw = ntile + quad * 4;
        const f32x4 nc4 = *(const f32x4*)(nc + nw);
        const f32x4 iv4 = *(const f32x4*)(inv_sigma2 + nw);
        f32x4 res;
        #pragma unroll
        for (int r = 0; r < 4; ++r) {
            float sq = fmaxf(nxm + nc4[r] - 2.0f * acc[r], 0.f);
            res[r] = __expf(-sq * iv4[r]);
        }
        *(f32x4*)&buf[l16][nw - n_base] = res;
    }

    __syncthreads();

    // Store-out: wave w emits rows w*4 .. w*4+3, each as ONE 1 KB
    // lane-contiguous dwordx4 store (fill-kernel geometry).
    #pragma unroll
    for (int i = 0; i < 4; ++i) {
        const int row = (wave << 2) + i;
        const f32x4 v = *(const f32x4*)&buf[row][lane << 2];
        *(f32x4*)(out + (size_t)(m_base + row) * N + n_base + (lane << 2)) = v;
    }
}

// ---------------- fallback: fully fused (R2's passing kernel) ----------------
__device__ __forceinline__ void split8(const float* __restrict__ p,
                                       bf16x8& hi, bf16x8& lo, float& ss) {
    #pragma unroll
    for (int j = 0; j < 8; ++j) {
        float v = p[j];
        ss = fmaf(v, v, ss);
        __hip_bfloat16 h = __float2bfloat16(v);
        float hf = __bfloat162float(h);
        __hip_bfloat16 l = __float2bfloat16(v - hf);
        hi[j] = *reinterpret_cast<const short*>(&h);
        lo[j] = *reinterpret_cast<const short*>(&l);
    }
}

__global__ __launch_bounds__(256) void rbf_fused(
    const float* __restrict__ x, const float* __restrict__ c,
    const float* __restrict__ ls, float* __restrict__ out, int N)
{
    const int wave = threadIdx.x >> 6;
    const int lane = threadIdx.x & 63;
    const int quad = lane >> 4;
    const int l16  = lane & 15;

    const int m_base = (blockIdx.y << 6) + (wave << 4);
    const int n_base = blockIdx.x << 6;

    const int am = m_base + l16;
    const float* xp = x + (size_t)am * K_DIM;
    bf16x8 ahi0, alo0, ahi1, alo1;
    float ssx = 0.f;
    split8(xp + quad * 8,      ahi0, alo0, ssx);
    split8(xp + 32 + quad * 8, ahi1, alo1, ssx);
    ssx += __shfl_xor(ssx, 16, 64);
    ssx += __shfl_xor(ssx, 32, 64);
    float nxr[4];
    #pragma unroll
    for (int r = 0; r < 4; ++r) nxr[r] = __shfl(ssx, quad * 4 + r, 64);

    #pragma unroll
    for (int nt = 0; nt < 4; ++nt) {
        const int n = n_base + nt * 16 + l16;
        const float* cp = c + (size_t)n * K_DIM;
        bf16x8 bhi0, blo0, bhi1, blo1;
        float ssc = 0.f;
        split8(cp + quad * 8,      bhi0, blo0, ssc);
        split8(cp + 32 + quad * 8, bhi1, blo1, ssc);
        ssc += __shfl_xor(ssc, 16, 64);
        ssc += __shfl_xor(ssc, 32, 64);

        f32x4 acc = {0.f, 0.f, 0.f, 0.f};
        acc = __builtin_amdgcn_mfma_f32_16x16x32_bf16(ahi0, bhi0, acc, 0, 0, 0);
        acc = __builtin_amdgcn_mfma_f32_16x16x32_bf16(ahi1, bhi1, acc, 0, 0, 0);
        acc = __builtin_amdgcn_mfma_f32_16x16x32_bf16(ahi0, blo0, acc, 0, 0, 0);
        acc = __builtin_amdgcn_mfma_f32_16x16x32_bf16(ahi1, blo1, acc, 0, 0, 0);
        acc = __builtin_amdgcn_mfma_f32_16x16x32_bf16(alo0, bhi0, acc, 0, 0, 0);
        acc = __builtin_amdgcn_mfma_f32_16x16x32_bf16(alo1, bhi1, acc, 0, 0, 0);

        const float invv = __expf(-2.0f * ls[n]);
        #pragma unroll
        for (int r = 0; r < 4; ++r) {
            const int row = m_base + quad * 4 + r;
            float sq = fmaxf(nxr[r] + ssc - 2.0f * acc[r], 0.f);
            out[(size_t)row * N + n] = __expf(-sq * invv);
        }
    }
}

extern "C" void kernel_launch(void* const* d_in, const int* in_sizes, int n_in,
                              void* d_out, int out_size, void* d_ws, size_t ws_size,
                              hipStream_t stream) {
    const float* x  = (const float*)d_in[0];   // [M,64]
    const float* c  = (const float*)d_in[1];   // [N,64]
    const float* ls = (const float*)d_in[2];   // [N]
    float* out = (float*)d_out;                // [M,N]

    const int M = in_sizes[0] / K_DIM;   // 16384
    const int N = in_sizes[2];           // 4096

    size_t off = 0;
    auto place = [&](size_t bytes) { size_t p = off; off += (bytes + 255) & ~(size_t)255; return p; };
    size_t o_xhi = place((size_t)M * K_DIM * 2);
    size_t o_xlo = place((size_t)M * K_DIM * 2);
    size_t o_chi = place((size_t)N * K_DIM * 2);
    size_t o_clo = place((size_t)N * K_DIM * 2);
    size_t o_nx  = place((size_t)M * 4);
    size_t o_nc  = place((size_t)N * 4);
    size_t o_inv = place((size_t)N * 4);

    if (ws_size >= off) {
        char* ws = (char*)d_ws;
        __hip_bfloat16* xhi = (__hip_bfloat16*)(ws + o_xhi);
        __hip_bfloat16* xlo = (__hip_bfloat16*)(ws + o_xlo);
        __hip_bfloat16* chi = (__hip_bfloat16*)(ws + o_chi);
        __hip_bfloat16* clo = (__hip_bfloat16*)(ws + o_clo);
        float* nx  = (float*)(ws + o_nx);
        float* nc  = (float*)(ws + o_nc);
        float* inv = (float*)(ws + o_inv);

        rbf_prep<<<dim3((M + 3) / 4), 256, 0, stream>>>(x, M, xhi, xlo, nx, nullptr, nullptr);
        rbf_prep<<<dim3((N + 3) / 4), 256, 0, stream>>>(c, N, chi, clo, nc, ls, inv);
        rbf_main<<<dim3(N / 256, M / 16), 256, 0, stream>>>(xhi, xlo, chi, clo, nx, nc, inv, out, N);
    } else {
        rbf_fused<<<dim3(N / 64, M / 64), 256, 0, stream>>>(x, c, ls, out, N);
    }
}

// Round 6
// 366.795 us; speedup vs baseline: 1.1044x; 1.0709x over previous
//
#include <hip/hip_runtime.h>
#include <hip/hip_bf16.h>

typedef __attribute__((ext_vector_type(8))) short bf16x8;
typedef __attribute__((ext_vector_type(4))) float f32x4;

#define K_DIM 64
#define LDSP  68   // 16 B-aligned pitch; write pattern 2-way (free), reads near b128 floor

// ---------------- prep: one wave per row ----------------
__global__ __launch_bounds__(256) void rbf_prep(
    const float* __restrict__ src, int rows,
    __hip_bfloat16* __restrict__ hi, __hip_bfloat16* __restrict__ lo,
    float* __restrict__ norms,
    const float* __restrict__ log_sigmas, float* __restrict__ inv_sigma2)
{
    int row  = blockIdx.x * 4 + (threadIdx.x >> 6);
    int lane = threadIdx.x & 63;
    if (row >= rows) return;

    float v = src[(size_t)row * K_DIM + lane];
    __hip_bfloat16 h = __float2bfloat16(v);
    float hf = __bfloat162float(h);
    __hip_bfloat16 l = __float2bfloat16(v - hf);
    hi[(size_t)row * K_DIM + lane] = h;
    lo[(size_t)row * K_DIM + lane] = l;

    float s = v * v;
    #pragma unroll
    for (int off = 32; off > 0; off >>= 1) s += __shfl_down(s, off, 64);
    if (lane == 0) {
        norms[row] = s;
        if (inv_sigma2) inv_sigma2[row] = __expf(-2.0f * log_sigmas[row]);
    }
}

// ---------------- main: row-band streamer ----------------
// Block b owns output rows [16b, 16b+16) x ALL 4096 cols, swept in 16 chunks
// of 256 cols (wave w handles cols [chunk + 64w, chunk + 64w + 64)).
// Per chunk: R4-verified MFMA orientation (A = centres, B = x;
// D: col(lane&15)->M row, row(quad*4+reg)->4 consecutive N cols), epilogue
// into a WAVE-PRIVATE LDS slice (same-wave producer/consumer -> NO BARRIERS,
// stores never drained by syncthreads), then 4 nontemporal dwordx4 stores
// covering rows 4i..4i+3 x 64 cols. Net effect per wave: 64 independent nt
// stores pipelined across the chunk loop, sequential block-local addresses —
// time-and-shape identical to the 6 TB/s fillBufferAligned stream.
__global__ __launch_bounds__(256, 4) void rbf_main(
    const __hip_bfloat16* __restrict__ xhi, const __hip_bfloat16* __restrict__ xlo,
    const __hip_bfloat16* __restrict__ chi, const __hip_bfloat16* __restrict__ clo,
    const float* __restrict__ nx, const float* __restrict__ nc,
    const float* __restrict__ inv_sigma2,
    float* __restrict__ out, int N)
{
    __shared__ float buf[4][16][LDSP];

    const int wave = threadIdx.x >> 6;
    const int lane = threadIdx.x & 63;
    const int quad = lane >> 4;
    const int l16  = lane & 15;

    const int m_base = blockIdx.x << 4;            // 16 rows per block

    // B fragments: the block's 16 x-rows, loaded once, live for the whole sweep.
    const int bm = m_base + l16;
    const bf16x8 xh0 = *(const bf16x8*)(xhi + (size_t)bm * K_DIM +      quad * 8);
    const bf16x8 xh1 = *(const bf16x8*)(xhi + (size_t)bm * K_DIM + 32 + quad * 8);
    const bf16x8 xl0 = *(const bf16x8*)(xlo + (size_t)bm * K_DIM +      quad * 8);
    const bf16x8 xl1 = *(const bf16x8*)(xlo + (size_t)bm * K_DIM + 32 + quad * 8);
    const float  nxm = nx[bm];

    for (int jx = 0; jx < 16; ++jx) {
        const int n_wave = (jx << 8) + (wave << 6);   // this wave's 64-col strip

        #pragma unroll
        for (int nt = 0; nt < 4; ++nt) {
            const int ntile = n_wave + (nt << 4);

            const int an = ntile + l16;
            const bf16x8 ch0 = *(const bf16x8*)(chi + (size_t)an * K_DIM +      quad * 8);
            const bf16x8 ch1 = *(const bf16x8*)(chi + (size_t)an * K_DIM + 32 + quad * 8);
            const bf16x8 cl0 = *(const bf16x8*)(clo + (size_t)an * K_DIM +      quad * 8);
            const bf16x8 cl1 = *(const bf16x8*)(clo + (size_t)an * K_DIM + 32 + quad * 8);

            f32x4 acc = {0.f, 0.f, 0.f, 0.f};
            acc = __builtin_amdgcn_mfma_f32_16x16x32_bf16(ch0, xh0, acc, 0, 0, 0);
            acc = __builtin_amdgcn_mfma_f32_16x16x32_bf16(ch1, xh1, acc, 0, 0, 0);
            acc = __builtin_amdgcn_mfma_f32_16x16x32_bf16(ch0, xl0, acc, 0, 0, 0);
            acc = __builtin_amdgcn_mfma_f32_16x16x32_bf16(ch1, xl1, acc, 0, 0, 0);
            acc = __builtin_amdgcn_mfma_f32_16x16x32_bf16(cl0, xh0, acc, 0, 0, 0);
            acc = __builtin_amdgcn_mfma_f32_16x16x32_bf16(cl1, xh1, acc, 0, 0, 0);

            const int nw = ntile + (quad << 2);
            const f32x4 nc4 = *(const f32x4*)(nc + nw);
            const f32x4 iv4 = *(const f32x4*)(inv_sigma2 + nw);
            f32x4 res;
            #pragma unroll
            for (int r = 0; r < 4; ++r) {
                float sq = fmaxf(nxm + nc4[r] - 2.0f * acc[r], 0.f);
                res[r] = __expf(-sq * iv4[r]);
            }
            // lane's 4 cols of row l16 within the wave's private 16x64 slice
            *(f32x4*)&buf[wave][l16][(nt << 4) + (quad << 2)] = res;
        }

        // Same-wave consume (lgkmcnt ordering only, no barrier): store-out
        // rows 4i..4i+3 x 64 cols as nontemporal dwordx4.
        #pragma unroll
        for (int i = 0; i < 4; ++i) {
            const int row = (i << 2) + (lane >> 4);
            const int col = (lane & 15) << 2;
            const f32x4 v = *(const f32x4*)&buf[wave][row][col];
            __builtin_nontemporal_store(
                v, (f32x4*)(out + (size_t)(m_base + row) * N + n_wave + col));
        }
    }
}

// ---------------- fallback: fully fused (R2's passing kernel) ----------------
__device__ __forceinline__ void split8(const float* __restrict__ p,
                                       bf16x8& hi, bf16x8& lo, float& ss) {
    #pragma unroll
    for (int j = 0; j < 8; ++j) {
        float v = p[j];
        ss = fmaf(v, v, ss);
        __hip_bfloat16 h = __float2bfloat16(v);
        float hf = __bfloat162float(h);
        __hip_bfloat16 l = __float2bfloat16(v - hf);
        hi[j] = *reinterpret_cast<const short*>(&h);
        lo[j] = *reinterpret_cast<const short*>(&l);
    }
}

__global__ __launch_bounds__(256) void rbf_fused(
    const float* __restrict__ x, const float* __restrict__ c,
    const float* __restrict__ ls, float* __restrict__ out, int N)
{
    const int wave = threadIdx.x >> 6;
    const int lane = threadIdx.x & 63;
    const int quad = lane >> 4;
    const int l16  = lane & 15;

    const int m_base = (blockIdx.y << 6) + (wave << 4);
    const int n_base = blockIdx.x << 6;

    const int am = m_base + l16;
    const float* xp = x + (size_t)am * K_DIM;
    bf16x8 ahi0, alo0, ahi1, alo1;
    float ssx = 0.f;
    split8(xp + quad * 8,      ahi0, alo0, ssx);
    split8(xp + 32 + quad * 8, ahi1, alo1, ssx);
    ssx += __shfl_xor(ssx, 16, 64);
    ssx += __shfl_xor(ssx, 32, 64);
    float nxr[4];
    #pragma unroll
    for (int r = 0; r < 4; ++r) nxr[r] = __shfl(ssx, quad * 4 + r, 64);

    #pragma unroll
    for (int nt = 0; nt < 4; ++nt) {
        const int n = n_base + nt * 16 + l16;
        const float* cp = c + (size_t)n * K_DIM;
        bf16x8 bhi0, blo0, bhi1, blo1;
        float ssc = 0.f;
        split8(cp + quad * 8,      bhi0, blo0, ssc);
        split8(cp + 32 + quad * 8, bhi1, blo1, ssc);
        ssc += __shfl_xor(ssc, 16, 64);
        ssc += __shfl_xor(ssc, 32, 64);

        f32x4 acc = {0.f, 0.f, 0.f, 0.f};
        acc = __builtin_amdgcn_mfma_f32_16x16x32_bf16(ahi0, bhi0, acc, 0, 0, 0);
        acc = __builtin_amdgcn_mfma_f32_16x16x32_bf16(ahi1, bhi1, acc, 0, 0, 0);
        acc = __builtin_amdgcn_mfma_f32_16x16x32_bf16(ahi0, blo0, acc, 0, 0, 0);
        acc = __builtin_amdgcn_mfma_f32_16x16x32_bf16(ahi1, blo1, acc, 0, 0, 0);
        acc = __builtin_amdgcn_mfma_f32_16x16x32_bf16(alo0, bhi0, acc, 0, 0, 0);
        acc = __builtin_amdgcn_mfma_f32_16x16x32_bf16(alo1, bhi1, acc, 0, 0, 0);

        const float invv = __expf(-2.0f * ls[n]);
        #pragma unroll
        for (int r = 0; r < 4; ++r) {
            const int row = m_base + quad * 4 + r;
            float sq = fmaxf(nxr[r] + ssc - 2.0f * acc[r], 0.f);
            out[(size_t)row * N + n] = __expf(-sq * invv);
        }
    }
}

extern "C" void kernel_launch(void* const* d_in, const int* in_sizes, int n_in,
                              void* d_out, int out_size, void* d_ws, size_t ws_size,
                              hipStream_t stream) {
    const float* x  = (const float*)d_in[0];   // [M,64]
    const float* c  = (const float*)d_in[1];   // [N,64]
    const float* ls = (const float*)d_in[2];   // [N]
    float* out = (float*)d_out;                // [M,N]

    const int M = in_sizes[0] / K_DIM;   // 16384
    const int N = in_sizes[2];           // 4096

    size_t off = 0;
    auto place = [&](size_t bytes) { size_t p = off; off += (bytes + 255) & ~(size_t)255; return p; };
    size_t o_xhi = place((size_t)M * K_DIM * 2);
    size_t o_xlo = place((size_t)M * K_DIM * 2);
    size_t o_chi = place((size_t)N * K_DIM * 2);
    size_t o_clo = place((size_t)N * K_DIM * 2);
    size_t o_nx  = place((size_t)M * 4);
    size_t o_nc  = place((size_t)N * 4);
    size_t o_inv = place((size_t)N * 4);

    if (ws_size >= off) {
        char* ws = (char*)d_ws;
        __hip_bfloat16* xhi = (__hip_bfloat16*)(ws + o_xhi);
        __hip_bfloat16* xlo = (__hip_bfloat16*)(ws + o_xlo);
        __hip_bfloat16* chi = (__hip_bfloat16*)(ws + o_chi);
        __hip_bfloat16* clo = (__hip_bfloat16*)(ws + o_clo);
        float* nx  = (float*)(ws + o_nx);
        float* nc  = (float*)(ws + o_nc);
        float* inv = (float*)(ws + o_inv);

        rbf_prep<<<dim3((M + 3) / 4), 256, 0, stream>>>(x, M, xhi, xlo, nx, nullptr, nullptr);
        rbf_prep<<<dim3((N + 3) / 4), 256, 0, stream>>>(c, N, chi, clo, nc, ls, inv);
        rbf_main<<<dim3(M / 16), 256, 0, stream>>>(xhi, xlo, chi, clo, nx, nc, inv, out, N);
    } else {
        rbf_fused<<<dim3(N / 64, M / 64), 256, 0, stream>>>(x, c, ls, out, N);
    }
}

// Round 7
// 360.331 us; speedup vs baseline: 1.1242x; 1.0179x over previous
//
#include <hip/hip_runtime.h>
#include <hip/hip_bf16.h>

typedef __attribute__((ext_vector_type(8))) short bf16x8;
typedef __attribute__((ext_vector_type(4))) float f32x4;

#define K_DIM 64
#define LDSP  68   // bounce-buffer pitch (floats)

// ---------------- prep: one wave per row ----------------
__global__ __launch_bounds__(256) void rbf_prep(
    const float* __restrict__ src, int rows,
    __hip_bfloat16* __restrict__ hi, __hip_bfloat16* __restrict__ lo,
    float* __restrict__ norms,
    const float* __restrict__ log_sigmas, float* __restrict__ inv_sigma2)
{
    int row  = blockIdx.x * 4 + (threadIdx.x >> 6);
    int lane = threadIdx.x & 63;
    if (row >= rows) return;

    float v = src[(size_t)row * K_DIM + lane];
    __hip_bfloat16 h = __float2bfloat16(v);
    float hf = __bfloat162float(h);
    __hip_bfloat16 l = __float2bfloat16(v - hf);
    hi[(size_t)row * K_DIM + lane] = h;
    lo[(size_t)row * K_DIM + lane] = l;

    float s = v * v;
    #pragma unroll
    for (int off = 32; off > 0; off >>= 1) s += __shfl_down(s, off, 64);
    if (lane == 0) {
        norms[row] = s;
        if (inv_sigma2) inv_sigma2[row] = __expf(-2.0f * log_sigmas[row]);
    }
}

// ---------------- main: row-band streamer, software-pipelined ----------------
// Block b owns rows [16b,16b+16) x all N cols, swept in 16 chunks of 256
// (wave w: cols [chunk+64w, chunk+64w+64)). R4-verified orientation
// (A=centres, B=x; D: col(lane&15)->M row, row(quad*4+reg)->4 consec N cols).
//
// KEY CHANGE vs R6: c-fragment loads for chunk jx+1 are issued BEFORE the
// stores of chunk jx (register double-buffer). vmcnt drains in order, so the
// compute wait at jx+1 no longer forces prior stores to complete — store
// completion is off the critical path and the store queue backs up across
// iterations (fill-kernel regime). nc/inv are staged to LDS once at start so
// the steady-state vmem queue is exactly [16 loads][4 nt-stores] per chunk.
__global__ __launch_bounds__(256, 2) void rbf_main(
    const __hip_bfloat16* __restrict__ xhi, const __hip_bfloat16* __restrict__ xlo,
    const __hip_bfloat16* __restrict__ chi, const __hip_bfloat16* __restrict__ clo,
    const float* __restrict__ nx, const float* __restrict__ nc,
    const float* __restrict__ inv_sigma2,
    float* __restrict__ out, int N)
{
    __shared__ float s_nc[4096];
    __shared__ float s_iv[4096];
    __shared__ float buf[4][16][LDSP];

    const int wave = threadIdx.x >> 6;
    const int lane = threadIdx.x & 63;
    const int quad = lane >> 4;
    const int l16  = lane & 15;

    // Stage nc/inv into LDS (removes them from the vmem queue forever).
    #pragma unroll
    for (int i = 0; i < 4; ++i) {
        const int idx = (i << 8) + threadIdx.x;           // 0..1023 f32x4 chunks
        ((f32x4*)s_nc)[idx] = ((const f32x4*)nc)[idx];
        ((f32x4*)s_iv)[idx] = ((const f32x4*)inv_sigma2)[idx];
    }
    __syncthreads();   // only barrier in the kernel

    const int m_base = blockIdx.x << 4;

    // x fragments: the block's 16 rows, live for the whole sweep.
    const int bm = m_base + l16;
    const bf16x8 xh0 = *(const bf16x8*)(xhi + (size_t)bm * K_DIM +      quad * 8);
    const bf16x8 xh1 = *(const bf16x8*)(xhi + (size_t)bm * K_DIM + 32 + quad * 8);
    const bf16x8 xl0 = *(const bf16x8*)(xlo + (size_t)bm * K_DIM +      quad * 8);
    const bf16x8 xl1 = *(const bf16x8*)(xlo + (size_t)bm * K_DIM + 32 + quad * 8);
    const float  nxm = nx[bm];

    // Per-lane base for c-fragment loads: row (wave*64 + l16), k-chunk quad*8.
    const __hip_bfloat16* chb = chi + (size_t)((wave << 6) + l16) * K_DIM + quad * 8;
    const __hip_bfloat16* clb = clo + (size_t)((wave << 6) + l16) * K_DIM + quad * 8;

    auto load_set = [&](int jx, bf16x8 h0[4], bf16x8 h1[4], bf16x8 l0[4], bf16x8 l1[4]) {
        const int base = jx * (256 * K_DIM);              // element offset of chunk
        #pragma unroll
        for (int nt = 0; nt < 4; ++nt) {
            const int o = base + nt * (16 * K_DIM);
            h0[nt] = *(const bf16x8*)(chb + o);
            h1[nt] = *(const bf16x8*)(chb + o + 32);
            l0[nt] = *(const bf16x8*)(clb + o);
            l1[nt] = *(const bf16x8*)(clb + o + 32);
        }
    };

    auto compute_store = [&](int jx, bf16x8 h0[4], bf16x8 h1[4], bf16x8 l0[4], bf16x8 l1[4]) {
        const int n_wave = (jx << 8) + (wave << 6);
        #pragma unroll
        for (int nt = 0; nt < 4; ++nt) {
            f32x4 acc = {0.f, 0.f, 0.f, 0.f};
            acc = __builtin_amdgcn_mfma_f32_16x16x32_bf16(h0[nt], xh0, acc, 0, 0, 0);
            acc = __builtin_amdgcn_mfma_f32_16x16x32_bf16(h1[nt], xh1, acc, 0, 0, 0);
            acc = __builtin_amdgcn_mfma_f32_16x16x32_bf16(h0[nt], xl0, acc, 0, 0, 0);
            acc = __builtin_amdgcn_mfma_f32_16x16x32_bf16(h1[nt], xl1, acc, 0, 0, 0);
            acc = __builtin_amdgcn_mfma_f32_16x16x32_bf16(l0[nt], xh0, acc, 0, 0, 0);
            acc = __builtin_amdgcn_mfma_f32_16x16x32_bf16(l1[nt], xh1, acc, 0, 0, 0);

            const int col = n_wave + (nt << 4) + (quad << 2);   // abs col of 4 outputs
            const f32x4 nc4 = *(const f32x4*)&s_nc[col];        // LDS (broadcast)
            const f32x4 iv4 = *(const f32x4*)&s_iv[col];
            f32x4 res;
            #pragma unroll
            for (int r = 0; r < 4; ++r) {
                float sq = fmaxf(nxm + nc4[r] - 2.0f * acc[r], 0.f);
                res[r] = __expf(-sq * iv4[r]);
            }
            *(f32x4*)&buf[wave][l16][(nt << 4) + (quad << 2)] = res;
        }
        // Same-wave consume (no barrier): 4 nontemporal 1 KB dwordx4 stores.
        #pragma unroll
        for (int i = 0; i < 4; ++i) {
            const int row = (i << 2) + (lane >> 4);
            const int col = (lane & 15) << 2;
            const f32x4 v = *(const f32x4*)&buf[wave][row][col];
            __builtin_nontemporal_store(
                v, (f32x4*)(out + (size_t)(m_base + row) * N + n_wave + col));
        }
    };

    bf16x8 Ah0[4], Ah1[4], Al0[4], Al1[4];
    bf16x8 Bh0[4], Bh1[4], Bl0[4], Bl1[4];

    load_set(0, Ah0, Ah1, Al0, Al1);
    #pragma unroll 1
    for (int jx = 0; jx < 16; jx += 2) {
        load_set(jx + 1, Bh0, Bh1, Bl0, Bl1);          // loads BEFORE stores(jx)
        compute_store(jx, Ah0, Ah1, Al0, Al1);
        load_set((jx + 2) & 15, Ah0, Ah1, Al0, Al1);   // loads BEFORE stores(jx+1)
        compute_store(jx + 1, Bh0, Bh1, Bl0, Bl1);
    }
}

// ---------------- fallback: fully fused (R2's passing kernel) ----------------
__device__ __forceinline__ void split8(const float* __restrict__ p,
                                       bf16x8& hi, bf16x8& lo, float& ss) {
    #pragma unroll
    for (int j = 0; j < 8; ++j) {
        float v = p[j];
        ss = fmaf(v, v, ss);
        __hip_bfloat16 h = __float2bfloat16(v);
        float hf = __bfloat162float(h);
        __hip_bfloat16 l = __float2bfloat16(v - hf);
        hi[j] = *reinterpret_cast<const short*>(&h);
        lo[j] = *reinterpret_cast<const short*>(&l);
    }
}

__global__ __launch_bounds__(256) void rbf_fused(
    const float* __restrict__ x, const float* __restrict__ c,
    const float* __restrict__ ls, float* __restrict__ out, int N)
{
    const int wave = threadIdx.x >> 6;
    const int lane = threadIdx.x & 63;
    const int quad = lane >> 4;
    const int l16  = lane & 15;

    const int m_base = (blockIdx.y << 6) + (wave << 4);
    const int n_base = blockIdx.x << 6;

    const int am = m_base + l16;
    const float* xp = x + (size_t)am * K_DIM;
    bf16x8 ahi0, alo0, ahi1, alo1;
    float ssx = 0.f;
    split8(xp + quad * 8,      ahi0, alo0, ssx);
    split8(xp + 32 + quad * 8, ahi1, alo1, ssx);
    ssx += __shfl_xor(ssx, 16, 64);
    ssx += __shfl_xor(ssx, 32, 64);
    float nxr[4];
    #pragma unroll
    for (int r = 0; r < 4; ++r) nxr[r] = __shfl(ssx, quad * 4 + r, 64);

    #pragma unroll
    for (int nt = 0; nt < 4; ++nt) {
        const int n = n_base + nt * 16 + l16;
        const float* cp = c + (size_t)n * K_DIM;
        bf16x8 bhi0, blo0, bhi1, blo1;
        float ssc = 0.f;
        split8(cp + quad * 8,      bhi0, blo0, ssc);
        split8(cp + 32 + quad * 8, bhi1, blo1, ssc);
        ssc += __shfl_xor(ssc, 16, 64);
        ssc += __shfl_xor(ssc, 32, 64);

        f32x4 acc = {0.f, 0.f, 0.f, 0.f};
        acc = __builtin_amdgcn_mfma_f32_16x16x32_bf16(ahi0, bhi0, acc, 0, 0, 0);
        acc = __builtin_amdgcn_mfma_f32_16x16x32_bf16(ahi1, bhi1, acc, 0, 0, 0);
        acc = __builtin_amdgcn_mfma_f32_16x16x32_bf16(ahi0, blo0, acc, 0, 0, 0);
        acc = __builtin_amdgcn_mfma_f32_16x16x32_bf16(ahi1, blo1, acc, 0, 0, 0);
        acc = __builtin_amdgcn_mfma_f32_16x16x32_bf16(alo0, bhi0, acc, 0, 0, 0);
        acc = __builtin_amdgcn_mfma_f32_16x16x32_bf16(alo1, bhi1, acc, 0, 0, 0);

        const float invv = __expf(-2.0f * ls[n]);
        #pragma unroll
        for (int r = 0; r < 4; ++r) {
            const int row = m_base + quad * 4 + r;
            float sq = fmaxf(nxr[r] + ssc - 2.0f * acc[r], 0.f);
            out[(size_t)row * N + n] = __expf(-sq * invv);
        }
    }
}

extern "C" void kernel_launch(void* const* d_in, const int* in_sizes, int n_in,
                              void* d_out, int out_size, void* d_ws, size_t ws_size,
                              hipStream_t stream) {
    const float* x  = (const float*)d_in[0];   // [M,64]
    const float* c  = (const float*)d_in[1];   // [N,64]
    const float* ls = (const float*)d_in[2];   // [N]
    float* out = (float*)d_out;                // [M,N]

    const int M = in_sizes[0] / K_DIM;   // 16384
    const int N = in_sizes[2];           // 4096

    size_t off = 0;
    auto place = [&](size_t bytes) { size_t p = off; off += (bytes + 255) & ~(size_t)255; return p; };
    size_t o_xhi = place((size_t)M * K_DIM * 2);
    size_t o_xlo = place((size_t)M * K_DIM * 2);
    size_t o_chi = place((size_t)N * K_DIM * 2);
    size_t o_clo = place((size_t)N * K_DIM * 2);
    size_t o_nx  = place((size_t)M * 4);
    size_t o_nc  = place((size_t)N * 4);
    size_t o_inv = place((size_t)N * 4);

    if (ws_size >= off) {
        char* ws = (char*)d_ws;
        __hip_bfloat16* xhi = (__hip_bfloat16*)(ws + o_xhi);
        __hip_bfloat16* xlo = (__hip_bfloat16*)(ws + o_xlo);
        __hip_bfloat16* chi = (__hip_bfloat16*)(ws + o_chi);
        __hip_bfloat16* clo = (__hip_bfloat16*)(ws + o_clo);
        float* nx  = (float*)(ws + o_nx);
        float* nc  = (float*)(ws + o_nc);
        float* inv = (float*)(ws + o_inv);

        rbf_prep<<<dim3((M + 3) / 4), 256, 0, stream>>>(x, M, xhi, xlo, nx, nullptr, nullptr);
        rbf_prep<<<dim3((N + 3) / 4), 256, 0, stream>>>(c, N, chi, clo, nc, ls, inv);
        rbf_main<<<dim3(M / 16), 256, 0, stream>>>(xhi, xlo, chi, clo, nx, nc, inv, out, N);
    } else {
        rbf_fused<<<dim3(N / 64, M / 64), 256, 0, stream>>>(x, c, ls, out, N);
    }
}